// Round 7
// baseline (429.634 us; speedup 1.0000x reference)
//
#include <hip/hip_runtime.h>

#define C_CH 4096
#define D_DIM 128

typedef float f32x2 __attribute__((ext_vector_type(2)));

// ---------------- K0: zero cnt, init first ----------------
__global__ __launch_bounds__(256) void init_kernel(int* cnt, int* first, int B) {
    int i = blockIdx.x * blockDim.x + threadIdx.x;
    if (i < C_CH) { cnt[i] = 0; first[i] = B - 1; }
}

// ---------------- K1: count + first via global atomics (int4, 4 ids/thread) ----
__global__ __launch_bounds__(256) void count_kernel(const int* __restrict__ ids,
                                                    int* cnt, int* first, int B) {
    int t = blockIdx.x * blockDim.x + threadIdx.x;
    int row = t * 4;
    if (row + 3 < B) {
        int4 v = ((const int4*)ids)[t];
        atomicAdd(&cnt[v.x], 1); atomicMin(&first[v.x], row + 0);
        atomicAdd(&cnt[v.y], 1); atomicMin(&first[v.y], row + 1);
        atomicAdd(&cnt[v.z], 1); atomicMin(&first[v.z], row + 2);
        atomicAdd(&cnt[v.w], 1); atomicMin(&first[v.w], row + 3);
    } else {
        for (int k = 0; k < 4; ++k)
            if (row + k < B) { int c = ids[row + k]; atomicAdd(&cnt[c], 1); atomicMin(&first[c], row + k); }
    }
}

// ---------------- K2: exclusive scan of 4096 counts -> offs, cursor ----------
__global__ void scan_kernel(const int* __restrict__ cnt, int* offs, int* cursor) {
    __shared__ int wtot[16];
    int tid  = threadIdx.x;
    int lane = tid & 63;
    int wave = tid >> 6;
    int base = tid * 4;
    int v0 = cnt[base + 0], v1 = cnt[base + 1], v2 = cnt[base + 2], v3 = cnt[base + 3];
    int s = v0 + v1 + v2 + v3;
    int inc = s;
    for (int off = 1; off < 64; off <<= 1) {
        int n = __shfl_up(inc, off, 64);
        if (lane >= off) inc += n;
    }
    if (lane == 63) wtot[wave] = inc;
    __syncthreads();
    if (wave == 0) {
        int t = (lane < 16) ? wtot[lane] : 0;
        int ts = t;
        for (int off = 1; off < 16; off <<= 1) {
            int n = __shfl_up(ts, off, 64);
            if (lane >= off) ts += n;
        }
        if (lane < 16) wtot[lane] = ts - t;
    }
    __syncthreads();
    int run = wtot[wave] + (inc - s);
    offs[base + 0] = run; cursor[base + 0] = run; run += v0;
    offs[base + 1] = run; cursor[base + 1] = run; run += v1;
    offs[base + 2] = run; cursor[base + 2] = run; run += v2;
    offs[base + 3] = run; cursor[base + 3] = run; run += v3;
    if (tid == 1023) offs[C_CH] = run;   // == B
}

// ---------------- K3: scatter row indices into channel-sorted order ----------
__global__ __launch_bounds__(256) void scatter_kernel(const int* __restrict__ ids,
                                                      int* cursor, int* order, int B) {
    int t = blockIdx.x * blockDim.x + threadIdx.x;
    int row = t * 4;
    if (row + 3 < B) {
        int4 v = ((const int4*)ids)[t];
        int p0 = atomicAdd(&cursor[v.x], 1);
        int p1 = atomicAdd(&cursor[v.y], 1);
        int p2 = atomicAdd(&cursor[v.z], 1);
        int p3 = atomicAdd(&cursor[v.w], 1);
        __builtin_nontemporal_store(row + 0, &order[p0]);
        __builtin_nontemporal_store(row + 1, &order[p1]);
        __builtin_nontemporal_store(row + 2, &order[p2]);
        __builtin_nontemporal_store(row + 3, &order[p3]);
    } else {
        for (int k = 0; k < 4; ++k)
            if (row + k < B) { int pos = atomicAdd(&cursor[ids[row + k]], 1); order[pos] = row + k; }
    }
}

// ---------------- K4: reduce — one WAVE per channel, 16 rows in flight,
// ---------------- index fetch double-buffered off the critical path ----------
__global__ __launch_bounds__(256) void reduce_kernel(
        const float* __restrict__ z, const int* __restrict__ order,
        const int* __restrict__ offs, const int* __restrict__ first,
        const int* __restrict__ y, float* __restrict__ out, int B) {
    int w = blockIdx.x * 4 + (threadIdx.x >> 6);   // channel
    int lane = threadIdx.x & 63;
    if (w >= C_CH) return;
    int beg = offs[w], end = offs[w + 1];
    const f32x2* z2 = (const f32x2*)z;

    f32x2 a0 = {0.f, 0.f}, a1 = {0.f, 0.f}, a2 = {0.f, 0.f}, a3 = {0.f, 0.f};
    f32x2 a4 = {0.f, 0.f}, a5 = {0.f, 0.f}, a6 = {0.f, 0.f}, a7 = {0.f, 0.f};

    if (end > beg) {
        int idx[16];
        #pragma unroll
        for (int k = 0; k < 16; ++k)
            idx[k] = order[min(beg + k, end - 1)];
        for (int r = beg; r < end; r += 16) {
            // issue z loads for current batch
            f32x2 v[16];
            #pragma unroll
            for (int k = 0; k < 16; ++k)
                v[k] = __builtin_nontemporal_load(&z2[(size_t)idx[k] * 64 + lane]);
            // prefetch next batch's indices while z loads are in flight
            int rn = r + 16;
            if (rn < end) {
                #pragma unroll
                for (int k = 0; k < 16; ++k)
                    idx[k] = order[min(rn + k, end - 1)];
            }
            // masked accumulate
            #pragma unroll
            for (int k = 0; k < 16; ++k) {
                if (r + k < end) {
                    switch (k & 7) {
                        case 0: a0 += v[k]; break;
                        case 1: a1 += v[k]; break;
                        case 2: a2 += v[k]; break;
                        case 3: a3 += v[k]; break;
                        case 4: a4 += v[k]; break;
                        case 5: a5 += v[k]; break;
                        case 6: a6 += v[k]; break;
                        case 7: a7 += v[k]; break;
                    }
                }
            }
        }
    }
    f32x2 sum = ((a0 + a1) + (a2 + a3)) + ((a4 + a5) + (a6 + a7));
    int cnt_c = end - beg;
    float inv = 1.f / (float)max(cnt_c, 1);
    f32x2 res; res.x = sum.x * inv; res.y = sum.y * inv;
    ((f32x2*)out)[(size_t)w * 64 + lane] = res;
    if (lane == 0) {
        out[(size_t)C_CH * D_DIM + w] = (float)y[min(first[w], B - 1)];
    }
}

// ---------------- launch ----------------
extern "C" void kernel_launch(void* const* d_in, const int* in_sizes, int n_in,
                              void* d_out, int out_size, void* d_ws, size_t ws_size,
                              hipStream_t stream) {
    const float* z   = (const float*)d_in[0];
    const int*   y   = (const int*)d_in[1];
    const int*   ids = (const int*)d_in[2];
    float* out = (float*)d_out;
    const int B = in_sizes[2];

    // workspace layout (ints): cnt | offs(+pad) | cursor | first | order
    int* cnt    = (int*)d_ws;           // 4096
    int* offs   = cnt + C_CH;           // 4097 (+3 pad)
    int* cursor = offs + C_CH + 4;      // 4096
    int* first  = cursor + C_CH;        // 4096
    int* order  = first + C_CH;         // B

    init_kernel<<<(C_CH + 255) / 256, 256, 0, stream>>>(cnt, first, B);
    int tquads = (B + 3) / 4;
    count_kernel<<<(tquads + 255) / 256, 256, 0, stream>>>(ids, cnt, first, B);
    scan_kernel<<<1, 1024, 0, stream>>>(cnt, offs, cursor);
    scatter_kernel<<<(tquads + 255) / 256, 256, 0, stream>>>(ids, cursor, order, B);
    reduce_kernel<<<C_CH / 4, 256, 0, stream>>>(z, order, offs, first, y, out, B);
}